// Round 9
// baseline (45898.972 us; speedup 1.0000x reference)
//
#include <hip/hip_runtime.h>
#include <hip/hip_fp16.h>

static constexpr int kH   = 2048;
static constexpr int kS   = 8192;
static constexpr int kNWG = 256;
static constexpr int kTHR = 512;

typedef float        v2f __attribute__((ext_vector_type(2)));
typedef unsigned int v4u __attribute__((ext_vector_type(4)));

__device__ __forceinline__ v2f unpk_bf(unsigned int u) {
    union { unsigned int i; float f; } lo, hi;
    lo.i = u << 16; hi.i = u & 0xffff0000u;
    v2f r; r[0] = lo.f; r[1] = hi.f; return r;
}
__device__ __forceinline__ unsigned int pkbf(float lo, float hi) {
    union { float f; unsigned int u; } a, b; a.f = lo; b.f = hi;
    unsigned int ar = a.u + 0x7fffu + ((a.u >> 16) & 1u);
    unsigned int br = b.u + 0x7fffu + ((b.u >> 16) & 1u);
    return (ar >> 16) | (br & 0xffff0000u);
}
__device__ __forceinline__ v2f cvt2h(unsigned int u) {
    __half2 h = *(__half2*)&u;
    float2 f = __half22float2(h);
    v2f r; r[0] = f.x; r[1] = f.y; return r;
}

// MALL-coherent poll: 4 x dwordx4, 1 KB lane-stride apart, single drain.
// RULES (r1/r5/r6/r8 lessons): wave 0 both polls and computes; polling bursts
// only in the post-publish window; publish grain is ONE 16B packet per WG;
// sync2 stays (it fences other waves' loads until after the publish store);
// nothing — loads OR FMAs — between publish and poll on wave 0.
__device__ __forceinline__ void poll4(const void* p, v4u& a, v4u& b, v4u& c, v4u& d) {
    asm volatile("global_load_dwordx4 %0, %4, off sc0 sc1\n\t"
                 "global_load_dwordx4 %1, %4, off offset:1024 sc0 sc1\n\t"
                 "global_load_dwordx4 %2, %4, off offset:2048 sc0 sc1\n\t"
                 "global_load_dwordx4 %3, %4, off offset:3072 sc0 sc1\n\t"
                 "s_waitcnt vmcnt(0)"
                 : "=&v"(a), "=&v"(b), "=&v"(c), "=&v"(d) : "v"(p) : "memory");
}
// Single 16B coherent store: h[8] as f16 + embedded toggle bit (one packet).
__device__ __forceinline__ void store16_coh(void* p, v4u v) {
    asm volatile("global_store_dwordx4 %0, %1, off sc0 sc1"
                 :: "v"(p), "v"(v) : "memory");
}

// 6-stage DPP wave64 sum; total lands in lane 63 (proven in round 4).
#define DPP_ADD(v, ctrl)                                                      \
    v += __int_as_float(__builtin_amdgcn_update_dpp(                          \
        0, __float_as_int(v), (ctrl), 0xf, 0xf, true))
#define RED_STAGE(ctrl) do { DPP_ADD(pr, ctrl); DPP_ADD(pz, ctrl);            \
                             DPP_ADD(pxn, ctrl); DPP_ADD(phn, ctrl); } while (0)
#define RED3_STAGE(ctrl) do { DPP_ADD(sr, ctrl); DPP_ADD(sz, ctrl);           \
                              DPP_ADD(sn, ctrl); } while (0)

// Persistent GRU. 256 WGs x 512 threads (8 waves), one WG per CU.
// Wave wv owns element e = wg*8+wv.
//   x-side: lane l covers cols 4l + 256m (m<8)
//   h-side: lane l covers cols 8l + 512m (m<4)  [b128-friendly]
// Publish protocol (= round 4, 18.16ms): WG's h[8] as f16 = ONE dwordx4
// record; toggle(s)=((s>>1)^s)&1 in record LSB; 2 parity slots kill ABA;
// wave 0 polls, sync1 releases, sync2 orders hpub vs tid0 publish.
//
// Round-9 change (single variable): wave 0 does NO x-projection — the x-row
// is the same data for all 8 elements, so wave 1 computes element-0's
// x-partials on the x-values it already loaded (zero extra loads), 3-chain
// DPP-reduces them, and lane 63 drops 3 floats in LDS — all inside wave 1's
// poll-wait shadow. Wave 0 goes publish -> poll with NOTHING in between and
// picks up its x-sums from LDS after sync1.
// Ordering: wave1 writes xsum(t) before sync1(t); wave0 reads after sync1(t)
// and before sync2(t); wave1's next write is after sync2(t). Single buffer.
__global__ __launch_bounds__(kTHR, 2)
void gru_persistent(const float* __restrict__ x,    // [S,H] f32
                    const float* __restrict__ Wih,  // [3H,H] f32
                    const float* __restrict__ Whh,  // [3H,H] f32
                    const float* __restrict__ bih,  // [3H] f32
                    const float* __restrict__ bhh,  // [3H] f32
                    float* __restrict__ out,        // [H] f32
                    unsigned char* __restrict__ rec) // 2 slots * 4096 B (zeroed)
{
    __shared__ __align__(16) unsigned short hlds[kH];  // h_t as f16, col c at [c]
    __shared__ __align__(16) unsigned short hpub[8];
    __shared__ __align__(16) float xsumf[4];           // e0 x-sums: r, z, n

    const int wg  = blockIdx.x;
    const int tid = threadIdx.x;
    const int wv  = tid >> 6;      // 0..7
    const int l   = tid & 63;      // 0..63
    const int e   = wg * 8 + wv;
    const int cb  = 4 * l;         // x-side col base
    const int hb  = 8 * l;         // h-side col base

    // Weights: W_hh slice as f32 pairs (96 regs, 8-col blocks),
    //          W_ih as packed bf16 (24 regs). Wave 1 additionally holds
    //          element-0's W_ih set (24 more) to cover wave 0's x-proj.
    v2f   whh2[3][4][4];
    uint2 wihp[3][8];
    uint2 wih0[3][8];
#pragma unroll
    for (int G = 0; G < 3; ++G) {
        const size_t row = (size_t)(G * kH + e) * kH;
#pragma unroll
        for (int m = 0; m < 4; ++m) {
            const size_t off = row + hb + 512 * m;
            const float4 w0 = *(const float4*)(Whh + off);
            const float4 w1 = *(const float4*)(Whh + off + 4);
            whh2[G][m][0][0] = w0.x; whh2[G][m][0][1] = w0.y;
            whh2[G][m][1][0] = w0.z; whh2[G][m][1][1] = w0.w;
            whh2[G][m][2][0] = w1.x; whh2[G][m][2][1] = w1.y;
            whh2[G][m][3][0] = w1.z; whh2[G][m][3][1] = w1.w;
        }
#pragma unroll
        for (int m = 0; m < 8; ++m) {
            const float4 iw = *(const float4*)(Wih + row + cb + 256 * m);
            wihp[G][m].x = pkbf(iw.x, iw.y);
            wihp[G][m].y = pkbf(iw.z, iw.w);
        }
    }
    if (wv == 1) {
#pragma unroll
        for (int G = 0; G < 3; ++G) {
            const size_t row0 = (size_t)(G * kH + wg * 8) * kH;
#pragma unroll
            for (int m = 0; m < 8; ++m) {
                const float4 iw = *(const float4*)(Wih + row0 + cb + 256 * m);
                wih0[G][m].x = pkbf(iw.x, iw.y);
                wih0[G][m].y = pkbf(iw.z, iw.w);
            }
        }
    }
    const float bir  = bih[e];
    const float biz  = bih[kH + e];
    const float bin_ = bih[2 * kH + e];
    const float bhr  = bhh[e];
    const float bhz  = bhh[kH + e];
    const float bhn  = bhh[2 * kH + e];

    float hold = 0.0f;  // h for element e (valid on l==63)

#pragma unroll 1
    for (int t = 0; t < kS; ++t) {
        // ---- x projection: waves 1-7 only (wave 0 goes straight to poll).
        //      Wave 1 also accumulates element-0's partials on the SAME
        //      x-values (zero extra loads), reduces, stages in LDS. ----
        v2f ar = {0.f, 0.f}, az = {0.f, 0.f}, an = {0.f, 0.f};
        if (wv != 0) {
            const float* xrow = x + (size_t)t * kH;
            v2f br = {0.f, 0.f}, bz = {0.f, 0.f}, bn = {0.f, 0.f};
#pragma unroll
            for (int m = 0; m < 8; ++m) {
                const float4 xv = *(const float4*)(xrow + cb + 256 * m);
                v2f x0; x0[0] = xv.x; x0[1] = xv.y;
                v2f x1; x1[0] = xv.z; x1[1] = xv.w;
                ar += unpk_bf(wihp[0][m].x) * x0 + unpk_bf(wihp[0][m].y) * x1;
                az += unpk_bf(wihp[1][m].x) * x0 + unpk_bf(wihp[1][m].y) * x1;
                an += unpk_bf(wihp[2][m].x) * x0 + unpk_bf(wihp[2][m].y) * x1;
                if (wv == 1) {
                    br += unpk_bf(wih0[0][m].x) * x0 + unpk_bf(wih0[0][m].y) * x1;
                    bz += unpk_bf(wih0[1][m].x) * x0 + unpk_bf(wih0[1][m].y) * x1;
                    bn += unpk_bf(wih0[2][m].x) * x0 + unpk_bf(wih0[2][m].y) * x1;
                }
            }
            if (wv == 1) {
                float sr = br[0] + br[1];
                float sz = bz[0] + bz[1];
                float sn = bn[0] + bn[1];
                RED3_STAGE(0xB1);  RED3_STAGE(0x4E);  RED3_STAGE(0x141);
                RED3_STAGE(0x140); RED3_STAGE(0x142); RED3_STAGE(0x143);
                if (l == 63) { xsumf[0] = sr; xsumf[1] = sz; xsumf[2] = sn; }
            }
        }

        // ---- wave 0: poll all 256 records for step-t toggle; data = payload ----
        if (tid < 64) {
            const unsigned int tg = (unsigned int)(((t >> 1) ^ t) & 1);
            const char* base = (const char*)rec + (t & 1) * 4096 + tid * 16;
            v4u r0, r1, r2, r3;
            for (;;) {
                poll4(base, r0, r1, r2, r3);
                const int ok = ((r0.x & 1u) == tg) & ((r1.x & 1u) == tg) &
                               ((r2.x & 1u) == tg) & ((r3.x & 1u) == tg);
                if (__all(ok)) break;
            }
            // broadcast h_t to LDS: lane i writes records i, i+64, i+128, i+192
            *(v4u*)&hlds[tid * 8]         = r0;
            *(v4u*)&hlds[(tid + 64) * 8]  = r1;
            *(v4u*)&hlds[(tid + 128) * 8] = r2;
            *(v4u*)&hlds[(tid + 192) * 8] = r3;
        }
        __syncthreads();   // sync1: orders hlds broadcast + xsum write vs reads

        // ---- wave 0: pick up element-0's x-sums (LDS broadcast read; the
        //      latency hides under h-proj, which is issued next) ----
        float xr0 = 0.f, xz0 = 0.f, xn0 = 0.f;
        if (wv == 0) { xr0 = xsumf[0]; xz0 = xsumf[1]; xn0 = xsumf[2]; }

        // ---- h projection from LDS f16: 4x ds_read_b128 per lane ----
        v2f hr = {0.f, 0.f}, hz = {0.f, 0.f}, hn = {0.f, 0.f};
#pragma unroll
        for (int m = 0; m < 4; ++m) {
            const v4u hu = *(const v4u*)&hlds[hb + 512 * m];
            const v2f h0 = cvt2h(hu.x);
            const v2f h1 = cvt2h(hu.y);
            const v2f h2 = cvt2h(hu.z);
            const v2f h3 = cvt2h(hu.w);
            hr += whh2[0][m][0] * h0 + whh2[0][m][1] * h1 +
                  whh2[0][m][2] * h2 + whh2[0][m][3] * h3;
            hz += whh2[1][m][0] * h0 + whh2[1][m][1] * h1 +
                  whh2[1][m][2] * h2 + whh2[1][m][3] * h3;
            hn += whh2[2][m][0] * h0 + whh2[2][m][1] * h1 +
                  whh2[2][m][2] * h2 + whh2[2][m][3] * h3;
        }

        // ---- full-wave DPP reduce (VALU pipe); sum lands in lane 63 ----
        // (wave 0's ar/az/an are exact zeros; its x-sums are added below.)
        float pr  = ar[0] + ar[1] + hr[0] + hr[1];
        float pz  = az[0] + az[1] + hz[0] + hz[1];
        float pxn = an[0] + an[1];
        float phn = hn[0] + hn[1];
        RED_STAGE(0xB1);   // quad_perm xor1
        RED_STAGE(0x4E);   // quad_perm xor2
        RED_STAGE(0x141);  // row_half_mirror
        RED_STAGE(0x140);  // row_mirror
        RED_STAGE(0x142);  // row_bcast15
        RED_STAGE(0x143);  // row_bcast31

        if (l == 63) {
            if (wv == 0) { pr += xr0; pz += xz0; pxn += xn0; }
            const float r = 1.f / (1.f + __expf(-(pr + bir + bhr)));
            const float z = 1.f / (1.f + __expf(-(pz + biz + bhz)));
            const float a = (pxn + bin_) + r * (phn + bhn);
            const float ee = __expf(-2.f * fabsf(a));
            float th = (1.f - ee) / (1.f + ee);
            th = (a < 0.f) ? -th : th;
            hold = (1.f - z) * th + z * hold;
            const __half hh = __float2half(hold);
            hpub[wv] = *(const unsigned short*)&hh;
        }
        __syncthreads();   // sync2: orders hpub writes vs tid0 pack+store,
                           // and fences waves 1-7's next x loads behind publish

        // ---- publish: ONE 16B coherent store (data + toggle in one packet) ----
        if (tid == 0) {
            v4u p = *(const v4u*)hpub;
            const unsigned int tgw = (unsigned int)((((t + 1) >> 1) ^ (t + 1)) & 1);
            p.x = (p.x & ~1u) | tgw;
            store16_coh((char*)rec + ((t + 1) & 1) * 4096 + wg * 16, p);
        }
    }

    if (l == 63)
        out[e] = hold;
}

extern "C" void kernel_launch(void* const* d_in, const int* in_sizes, int n_in,
                              void* d_out, int out_size, void* d_ws, size_t ws_size,
                              hipStream_t stream) {
    (void)in_sizes; (void)n_in; (void)out_size; (void)ws_size;
    const float* x   = (const float*)d_in[0];
    const float* Wih = (const float*)d_in[1];
    const float* Whh = (const float*)d_in[2];
    const float* bih = (const float*)d_in[3];
    const float* bhh = (const float*)d_in[4];

    unsigned char* rec = (unsigned char*)d_ws;   // 2 slots * 4096 B
    hipMemsetAsync(rec, 0, 8192, stream);        // h_0 = 0, slot-0 toggle 0; slot-1 waits
    gru_persistent<<<dim3(kNWG), dim3(kTHR), 0, stream>>>(
        x, Wih, Whh, bih, bhh, (float*)d_out, rec);
}

// Round 10
// 16630.804 us; speedup vs baseline: 2.7599x; 2.7599x over previous
//
#include <hip/hip_runtime.h>
#include <hip/hip_fp16.h>

static constexpr int kH   = 2048;
static constexpr int kS   = 8192;
static constexpr int kNWG = 256;
static constexpr int kTHR = 512;

typedef float        v2f __attribute__((ext_vector_type(2)));
typedef unsigned int v4u __attribute__((ext_vector_type(4)));
typedef _Float16     h2  __attribute__((ext_vector_type(2)));

__device__ __forceinline__ v2f unpk_bf(unsigned int u) {
    union { unsigned int i; float f; } lo, hi;
    lo.i = u << 16; hi.i = u & 0xffff0000u;
    v2f r; r[0] = lo.f; r[1] = hi.f; return r;
}
__device__ __forceinline__ unsigned int pkbf(float lo, float hi) {
    union { float f; unsigned int u; } a, b; a.f = lo; b.f = hi;
    unsigned int ar = a.u + 0x7fffu + ((a.u >> 16) & 1u);
    unsigned int br = b.u + 0x7fffu + ((b.u >> 16) & 1u);
    return (ar >> 16) | (br & 0xffff0000u);
}
__device__ __forceinline__ h2 as_h2(unsigned int u) {
    union { unsigned int i; h2 h; } c; c.i = u; return c.h;
}

// MALL-coherent poll: 4 x dwordx4, 1 KB lane-stride apart, single drain.
// CHOREOGRAPHY RULES (r1/r5/r6/r8/r9 lessons — 6 regressions defending them):
//  * wave 0 both polls and computes (dedicated pollers congest: r5, r6);
//  * x-proj sits BETWEEN publish and poll — it is the pacing gap that lets
//    the publish store propagate before the poll flood (r9: removing it
//    cost 2.5x, WRITE +67%);
//  * sync2 stays — it fences waves 1-7's next x loads behind the publish
//    store (r8: removing it cost 1.36x);
//  * publish grain is ONE 16B line-packet per WG (r5: fragmenting cost 5.5x);
//  * poll bursts only in the post-x-proj window (r1: early/continuous
//    polling cost 1.7x).
__device__ __forceinline__ void poll4(const void* p, v4u& a, v4u& b, v4u& c, v4u& d) {
    asm volatile("global_load_dwordx4 %0, %4, off sc0 sc1\n\t"
                 "global_load_dwordx4 %1, %4, off offset:1024 sc0 sc1\n\t"
                 "global_load_dwordx4 %2, %4, off offset:2048 sc0 sc1\n\t"
                 "global_load_dwordx4 %3, %4, off offset:3072 sc0 sc1\n\t"
                 "s_waitcnt vmcnt(0)"
                 : "=&v"(a), "=&v"(b), "=&v"(c), "=&v"(d) : "v"(p) : "memory");
}
// Single 16B coherent store: h[8] as f16 + embedded toggle bit (one packet).
__device__ __forceinline__ void store16_coh(void* p, v4u v) {
    asm volatile("global_store_dwordx4 %0, %1, off sc0 sc1"
                 :: "v"(p), "v"(v) : "memory");
}

// 6-stage DPP wave64 sum; total lands in lane 63 (proven in round 4).
#define DPP_ADD(v, ctrl)                                                      \
    v += __int_as_float(__builtin_amdgcn_update_dpp(                          \
        0, __float_as_int(v), (ctrl), 0xf, 0xf, true))
#define RED_STAGE(ctrl) do { DPP_ADD(pr, ctrl); DPP_ADD(pz, ctrl);            \
                             DPP_ADD(pxn, ctrl); DPP_ADD(phn, ctrl); } while (0)

// Persistent GRU. 256 WGs x 512 threads (8 waves), one WG per CU.
// Wave wv owns element e = wg*8+wv.
//   x-side: lane l covers cols 4l + 256m (m<8)   [f32 x, bf16-packed W_ih]
//   h-side: lane l covers cols 8l + 512m (m<4)   [f16 LDS, f16 W_hh]
// Publish protocol (= round 4, 18.16ms): WG's h[8] as f16 = ONE dwordx4
// record; toggle(s)=((s>>1)^s)&1 in record LSB; 2 parity slots kill ABA;
// wave 0 polls, sync1 releases, sync2 orders hpub vs tid0 publish.
//
// Round-10 change (SINGLE variable, isolating r8's change (a)): h-proj uses
// v_dot2_f32_f16 — consumes LDS f16 pairs directly with f32 accumulate,
// removing 32 v_cvt_f32_f16 from the post-sync1 serial segment; W_hh held
// as f16 (48 VGPRs, was 96). Numerics proven in r8 (absmax 0.00390625).
// Everything else byte-identical to round 4.
__global__ __launch_bounds__(kTHR, 2)
void gru_persistent(const float* __restrict__ x,    // [S,H] f32
                    const float* __restrict__ Wih,  // [3H,H] f32
                    const float* __restrict__ Whh,  // [3H,H] f32
                    const float* __restrict__ bih,  // [3H] f32
                    const float* __restrict__ bhh,  // [3H] f32
                    float* __restrict__ out,        // [H] f32
                    unsigned char* __restrict__ rec) // 2 slots * 4096 B (zeroed)
{
    __shared__ __align__(16) unsigned short hlds[kH];  // h_t as f16, col c at [c]
    __shared__ __align__(16) unsigned short hpub[8];

    const int wg  = blockIdx.x;
    const int tid = threadIdx.x;
    const int wv  = tid >> 6;      // 0..7
    const int l   = tid & 63;      // 0..63
    const int e   = wg * 8 + wv;
    const int cb  = 4 * l;         // x-side col base
    const int hb  = 8 * l;         // h-side col base

    // Weights: W_hh slice as f16 pairs (48 regs, 8-col blocks),
    //          W_ih as packed bf16 (24 regs, 4-col blocks).
    h2    whhh[3][4][4];
    uint2 wihp[3][8];
#pragma unroll
    for (int G = 0; G < 3; ++G) {
        const size_t row = (size_t)(G * kH + e) * kH;
#pragma unroll
        for (int m = 0; m < 4; ++m) {
            const size_t off = row + hb + 512 * m;
            const float4 w0 = *(const float4*)(Whh + off);
            const float4 w1 = *(const float4*)(Whh + off + 4);
            h2 t0; t0[0] = (_Float16)w0.x; t0[1] = (_Float16)w0.y;
            h2 t1; t1[0] = (_Float16)w0.z; t1[1] = (_Float16)w0.w;
            h2 t2; t2[0] = (_Float16)w1.x; t2[1] = (_Float16)w1.y;
            h2 t3; t3[0] = (_Float16)w1.z; t3[1] = (_Float16)w1.w;
            whhh[G][m][0] = t0; whhh[G][m][1] = t1;
            whhh[G][m][2] = t2; whhh[G][m][3] = t3;
        }
#pragma unroll
        for (int m = 0; m < 8; ++m) {
            const float4 iw = *(const float4*)(Wih + row + cb + 256 * m);
            wihp[G][m].x = pkbf(iw.x, iw.y);
            wihp[G][m].y = pkbf(iw.z, iw.w);
        }
    }
    const float bir  = bih[e];
    const float biz  = bih[kH + e];
    const float bin_ = bih[2 * kH + e];
    const float bhr  = bhh[e];
    const float bhz  = bhh[kH + e];
    const float bhn  = bhh[2 * kH + e];

    float hold = 0.0f;  // h for element e (valid on l==63)

#pragma unroll 1
    for (int t = 0; t < kS; ++t) {
        // ---- x projection (cached loads; the pacing gap between publish(t)
        //      and poll(t) — load-bearing, see rules above) ----
        const float* xrow = x + (size_t)t * kH;
        v2f ar = {0.f, 0.f}, az = {0.f, 0.f}, an = {0.f, 0.f};
#pragma unroll
        for (int m = 0; m < 8; ++m) {
            const float4 xv = *(const float4*)(xrow + cb + 256 * m);
            v2f x0; x0[0] = xv.x; x0[1] = xv.y;
            v2f x1; x1[0] = xv.z; x1[1] = xv.w;
            ar += unpk_bf(wihp[0][m].x) * x0 + unpk_bf(wihp[0][m].y) * x1;
            az += unpk_bf(wihp[1][m].x) * x0 + unpk_bf(wihp[1][m].y) * x1;
            an += unpk_bf(wihp[2][m].x) * x0 + unpk_bf(wihp[2][m].y) * x1;
        }

        // ---- wave 0: poll all 256 records for step-t toggle; data = payload ----
        if (tid < 64) {
            const unsigned int tg = (unsigned int)(((t >> 1) ^ t) & 1);
            const char* base = (const char*)rec + (t & 1) * 4096 + tid * 16;
            v4u r0, r1, r2, r3;
            for (;;) {
                poll4(base, r0, r1, r2, r3);
                const int ok = ((r0.x & 1u) == tg) & ((r1.x & 1u) == tg) &
                               ((r2.x & 1u) == tg) & ((r3.x & 1u) == tg);
                if (__all(ok)) break;
            }
            // broadcast h_t to LDS: lane i writes records i, i+64, i+128, i+192
            *(v4u*)&hlds[tid * 8]         = r0;
            *(v4u*)&hlds[(tid + 64) * 8]  = r1;
            *(v4u*)&hlds[(tid + 128) * 8] = r2;
            *(v4u*)&hlds[(tid + 192) * 8] = r3;
        }
        __syncthreads();   // sync1: orders hlds broadcast vs h-proj reads

        // ---- h projection from LDS f16: 4x ds_read_b128 + v_dot2_f32_f16 ----
        float hr = 0.f, hz = 0.f, hn = 0.f;
#pragma unroll
        for (int m = 0; m < 4; ++m) {
            const v4u hu = *(const v4u*)&hlds[hb + 512 * m];
            const h2 h0  = as_h2(hu.x);
            const h2 h1  = as_h2(hu.y);
            const h2 h2v = as_h2(hu.z);
            const h2 h3  = as_h2(hu.w);
            hr = __builtin_amdgcn_fdot2(whhh[0][m][0], h0,  hr, false);
            hz = __builtin_amdgcn_fdot2(whhh[1][m][0], h0,  hz, false);
            hn = __builtin_amdgcn_fdot2(whhh[2][m][0], h0,  hn, false);
            hr = __builtin_amdgcn_fdot2(whhh[0][m][1], h1,  hr, false);
            hz = __builtin_amdgcn_fdot2(whhh[1][m][1], h1,  hz, false);
            hn = __builtin_amdgcn_fdot2(whhh[2][m][1], h1,  hn, false);
            hr = __builtin_amdgcn_fdot2(whhh[0][m][2], h2v, hr, false);
            hz = __builtin_amdgcn_fdot2(whhh[1][m][2], h2v, hz, false);
            hn = __builtin_amdgcn_fdot2(whhh[2][m][2], h2v, hn, false);
            hr = __builtin_amdgcn_fdot2(whhh[0][m][3], h3,  hr, false);
            hz = __builtin_amdgcn_fdot2(whhh[1][m][3], h3,  hz, false);
            hn = __builtin_amdgcn_fdot2(whhh[2][m][3], h3,  hn, false);
        }

        // ---- full-wave DPP reduce (VALU pipe); sum lands in lane 63 ----
        float pr  = ar[0] + ar[1] + hr;
        float pz  = az[0] + az[1] + hz;
        float pxn = an[0] + an[1];
        float phn = hn;
        RED_STAGE(0xB1);   // quad_perm xor1
        RED_STAGE(0x4E);   // quad_perm xor2
        RED_STAGE(0x141);  // row_half_mirror
        RED_STAGE(0x140);  // row_mirror
        RED_STAGE(0x142);  // row_bcast15
        RED_STAGE(0x143);  // row_bcast31

        if (l == 63) {
            const float r = 1.f / (1.f + __expf(-(pr + bir + bhr)));
            const float z = 1.f / (1.f + __expf(-(pz + biz + bhz)));
            const float a = (pxn + bin_) + r * (phn + bhn);
            const float ee = __expf(-2.f * fabsf(a));
            float th = (1.f - ee) / (1.f + ee);
            th = (a < 0.f) ? -th : th;
            hold = (1.f - z) * th + z * hold;
            const __half hh = __float2half(hold);
            hpub[wv] = *(const unsigned short*)&hh;
        }
        __syncthreads();   // sync2: orders hpub writes vs tid0 pack+store,
                           // and fences waves 1-7's next x loads behind publish

        // ---- publish: ONE 16B coherent store (data + toggle in one packet) ----
        if (tid == 0) {
            v4u p = *(const v4u*)hpub;
            const unsigned int tgw = (unsigned int)((((t + 1) >> 1) ^ (t + 1)) & 1);
            p.x = (p.x & ~1u) | tgw;
            store16_coh((char*)rec + ((t + 1) & 1) * 4096 + wg * 16, p);
        }
    }

    if (l == 63)
        out[e] = hold;
}

extern "C" void kernel_launch(void* const* d_in, const int* in_sizes, int n_in,
                              void* d_out, int out_size, void* d_ws, size_t ws_size,
                              hipStream_t stream) {
    (void)in_sizes; (void)n_in; (void)out_size; (void)ws_size;
    const float* x   = (const float*)d_in[0];
    const float* Wih = (const float*)d_in[1];
    const float* Whh = (const float*)d_in[2];
    const float* bih = (const float*)d_in[3];
    const float* bhh = (const float*)d_in[4];

    unsigned char* rec = (unsigned char*)d_ws;   // 2 slots * 4096 B
    hipMemsetAsync(rec, 0, 8192, stream);        // h_0 = 0, slot-0 toggle 0; slot-1 waits
    gru_persistent<<<dim3(kNWG), dim3(kTHR), 0, stream>>>(
        x, Wih, Whh, bih, bhh, (float*)d_out, rec);
}